// Round 5
// baseline (424.279 us; speedup 1.0000x reference)
//
#include <hip/hip_runtime.h>
#include <math.h>

#define B 256
#define SDIM 1024
#define TDIM 2048
#define C 128
#define NCLS 100
#define KNEG 4096
#define KNN_K 8
#define NCHUNK 16
#define KC (KNEG / NCHUNK)   // 256 rows per block
#define TINV (1.0f / 0.07f)

// ---------------------------------------------------------------------------
// DPP helpers: cross-lane sums on the VALU pipe.
// ---------------------------------------------------------------------------
template <int CTRL>
__device__ __forceinline__ float dpp_add(float v) {
  const int x = __builtin_amdgcn_update_dpp(0, __float_as_int(v), CTRL, 0xF, 0xF, true);
  return v + __int_as_float(x);
}
__device__ __forceinline__ float sum16(float v) {
  v = dpp_add<0xB1>(v);   // quad_perm [1,0,3,2]
  v = dpp_add<0x4E>(v);   // quad_perm [2,3,0,1]
  v = dpp_add<0x141>(v);  // row_half_mirror
  v = dpp_add<0x140>(v);  // row_mirror
  return v;
}
__device__ __forceinline__ float wave_sum64(float v) {
  v = sum16(v);
  v += __shfl_xor(v, 16, 64);
  v += __shfl_xor(v, 32, 64);
  return v;
}
__device__ __forceinline__ float dot4(float4 a, float4 b) {
  return a.x * b.x + a.y * b.y + a.z * b.z + a.w * b.w;
}

// ---------------------------------------------------------------------------
// Per-b deterministic bitonic sort of the 4096 contrast indices by row id.
// Key = (row << 12) | k  (row < 2^18, k < 2^12) -> unique keys -> total order
// -> result independent of thread timing. Output: rows only, ascending.
// Purpose: all concurrent neg_partial blocks then walk the same narrow row
// window of the memory banks -> L3 working set shrinks from 205 MB to the
// aligned window -> L3 hit rate -> ~1, HBM fetch -> compulsory-only.
// ---------------------------------------------------------------------------
__global__ __launch_bounds__(1024) void sort_refs_kernel(
    const int* __restrict__ cidx, int* __restrict__ sorted_rows) {
  __shared__ unsigned key[KNEG];  // 16 KB
  const int b = blockIdx.x;
  const int t = threadIdx.x;

  for (int i = t; i < KNEG; i += 1024)
    key[i] = ((unsigned)cidx[(size_t)b * KNEG + i] << 12) | (unsigned)i;
  __syncthreads();

  for (int k2 = 2; k2 <= KNEG; k2 <<= 1) {
    for (int j = k2 >> 1; j > 0; j >>= 1) {
#pragma unroll
      for (int s = 0; s < KNEG / 1024; ++s) {
        const int i = s * 1024 + t;
        const int ixj = i ^ j;
        if (ixj > i) {
          const bool up = ((i & k2) == 0);
          const unsigned a = key[i], c = key[ixj];
          if ((a > c) == up) { key[i] = c; key[ixj] = a; }
        }
      }
      __syncthreads();
    }
  }
  for (int i = t; i < KNEG; i += 1024)
    sorted_rows[(size_t)b * KNEG + i] = (int)(key[i] >> 12);
}

// ---------------------------------------------------------------------------
// Fused embed, 4 batch rows per block: out[b,:] = l2norm(X[b,:] @ W^T + bias)
// grid (B/4, 2): y=0 -> (f_s,W_es), y=1 -> (f_t,W_et). 256 thr = 4 waves.
// ---------------------------------------------------------------------------
__global__ __launch_bounds__(256) void embed2_kernel(
    const float* __restrict__ Xs, const float* __restrict__ Ws,
    const float* __restrict__ bs, const float* __restrict__ Xt,
    const float* __restrict__ Wt, const float* __restrict__ bt,
    float* __restrict__ out_s, float* __restrict__ out_t) {
  const int which = blockIdx.y;
  const int S = which ? TDIM : SDIM;
  const float* __restrict__ X = which ? Xt : Xs;
  const float* __restrict__ W = which ? Wt : Ws;
  const float* __restrict__ bias = which ? bt : bs;
  float* __restrict__ out = which ? out_t : out_s;

  __shared__ float xrow[4 * TDIM];
  __shared__ float ob[4][C];
  const int b4 = blockIdx.x * 4;
  const int t = threadIdx.x;
  const int wave = t >> 6, lane = t & 63;

  const float4* xg = (const float4*)(X + (size_t)b4 * S);
  for (int i = t; i < S; i += 256) ((float4*)xrow)[i] = xg[i];
  __syncthreads();

  const int nj = S / 256;
  const int sq = S / 4;
  for (int ci = 0; ci < 32; ++ci) {
    const int c = wave * 32 + ci;
    const float4* wrow = (const float4*)(W + (size_t)c * S);
    float a0 = 0.f, a1 = 0.f, a2 = 0.f, a3 = 0.f;
    for (int j = 0; j < nj; ++j) {
      const float4 w4 = wrow[lane + 64 * j];
      a0 += dot4(w4, ((const float4*)xrow)[0 * sq + lane + 64 * j]);
      a1 += dot4(w4, ((const float4*)xrow)[1 * sq + lane + 64 * j]);
      a2 += dot4(w4, ((const float4*)xrow)[2 * sq + lane + 64 * j]);
      a3 += dot4(w4, ((const float4*)xrow)[3 * sq + lane + 64 * j]);
    }
    a0 = wave_sum64(a0); a1 = wave_sum64(a1);
    a2 = wave_sum64(a2); a3 = wave_sum64(a3);
    if (lane == 0) {
      const float bb = bias[c];
      ob[0][c] = a0 + bb; ob[1][c] = a1 + bb;
      ob[2][c] = a2 + bb; ob[3][c] = a3 + bb;
    }
  }
  __syncthreads();

  const float v1 = ob[wave][lane];
  const float v2 = ob[wave][lane + 64];
  const float ss = wave_sum64(v1 * v1 + v2 * v2);
  const float inv = 1.0f / sqrtf(ss);
  out[(size_t)(b4 + wave) * C + lane] = v1 * inv;
  out[(size_t)(b4 + wave) * C + lane + 64] = v2 * inv;
}

// ---------------------------------------------------------------------------
// knn part 1: row softmax of logits [B,NCLS] + L2 norm of softmax row.
// ---------------------------------------------------------------------------
__global__ __launch_bounds__(128) void knn_soft_kernel(
    const float* __restrict__ Ls, const float* __restrict__ Lt,
    float* __restrict__ soft_s, float* __restrict__ soft_t,
    float* __restrict__ wn_s, float* __restrict__ wn_t) {
  const int which = blockIdx.y;
  const float* L = which ? Lt : Ls;
  float* soft = which ? soft_t : soft_s;
  float* wn = which ? wn_t : wn_s;
  const int b = blockIdx.x;
  const int t = threadIdx.x;
  const int wave = t >> 6, lane = t & 63;
  __shared__ float r2[2];

  const float x = (t < NCLS) ? L[b * NCLS + t] : -INFINITY;
  float m = x;
#pragma unroll
  for (int off = 32; off; off >>= 1) m = fmaxf(m, __shfl_xor(m, off, 64));
  if (lane == 0) r2[wave] = m;
  __syncthreads();
  m = fmaxf(r2[0], r2[1]);
  __syncthreads();

  const float e = (t < NCLS) ? expf(x - m) : 0.f;
  float s = e;
#pragma unroll
  for (int off = 32; off; off >>= 1) s += __shfl_xor(s, off, 64);
  if (lane == 0) r2[wave] = s;
  __syncthreads();
  s = r2[0] + r2[1];
  __syncthreads();

  const float p = e / s;
  if (t < NCLS) soft[b * NCLS + t] = p;

  float q = p * p;
#pragma unroll
  for (int off = 32; off; off >>= 1) q += __shfl_xor(q, off, 64);
  if (lane == 0) r2[wave] = q;
  __syncthreads();
  if (t == 0) wn[b] = sqrtf(r2[0] + r2[1]);
}

// ---------------------------------------------------------------------------
// knn part 2: top-8 neighbor set per row. grid (B, 2), 256 threads.
// ---------------------------------------------------------------------------
__global__ __launch_bounds__(256) void knn_topk_kernel(
    const float* __restrict__ soft_s, const float* __restrict__ wn_s,
    int* __restrict__ nbr_s, const float* __restrict__ soft_t,
    const float* __restrict__ wn_t, int* __restrict__ nbr_t) {
  const int which = blockIdx.y;
  const float* __restrict__ soft = which ? soft_t : soft_s;
  const float* __restrict__ wn = which ? wn_t : wn_s;
  int* __restrict__ nbr = which ? nbr_t : nbr_s;

  const int i = blockIdx.x;
  const int j = threadIdx.x;
  __shared__ float si[NCLS];
  __shared__ float vals[B];

  if (j < NCLS) si[j] = soft[i * NCLS + j];
  __syncthreads();

  float dot = 0.f;
  const float4* sj4 = (const float4*)(soft + j * NCLS);
#pragma unroll
  for (int c = 0; c < NCLS / 4; ++c) dot += dot4(((const float4*)si)[c], sj4[c]);
  const float denom = fmaxf(wn[i] * wn[j], 1e-7f);
  vals[j] = (j == i) ? 1.0f : (dot / denom - 1.0f);
  __syncthreads();

  if (j < 64) {
    float v0 = vals[j], v1 = vals[j + 64], v2 = vals[j + 128], v3 = vals[j + 192];
    for (int r = 0; r < KNN_K; ++r) {
      float bv = v0; int bi = j;
      if (v1 > bv) { bv = v1; bi = j + 64; }
      if (v2 > bv) { bv = v2; bi = j + 128; }
      if (v3 > bv) { bv = v3; bi = j + 192; }
#pragma unroll
      for (int off = 1; off < 64; off <<= 1) {
        const float ov = __shfl_xor(bv, off, 64);
        const int oi = __shfl_xor(bi, off, 64);
        if (ov > bv || (ov == bv && oi < bi)) { bv = ov; bi = oi; }
      }
      if (j == 0) nbr[i * KNN_K + r] = bi;
      if (j == (bi & 63)) {
        const int q = bi >> 6;
        if (q == 0) v0 = -INFINITY;
        else if (q == 1) v1 = -INFINITY;
        else if (q == 2) v2 = -INFINITY;
        else v3 = -INFINITY;
      }
    }
  }
}

// ---------------------------------------------------------------------------
// Fused TAGConv(k=1)+l2norm for BOTH branches + all four positive logits.
// ---------------------------------------------------------------------------
__global__ __launch_bounds__(256) void gnn_pos_kernel(
    const float* __restrict__ f_es, const float* __restrict__ f_et,
    const int* __restrict__ nbr_s, const int* __restrict__ nbr_t,
    const float* __restrict__ W_gs, const float* __restrict__ b_gs,
    const float* __restrict__ W_gt, const float* __restrict__ b_gt,
    const float* __restrict__ mem_l, const float* __restrict__ mem_ab,
    const int* __restrict__ idx, float* __restrict__ f_gs_out,
    float* __restrict__ f_gt_out, float* __restrict__ pos) {
  const int b = blockIdx.x;
  const int t = threadIdx.x;
  const int half = t >> 7;
  const int c = t & 127;
  const int wave = t >> 6, lane = t & 63;

  const float* __restrict__ h = half ? f_et : f_es;
  const int* __restrict__ nbr = half ? nbr_t : nbr_s;
  const float* __restrict__ Wg = half ? W_gt : W_gs;
  const float* __restrict__ bg = half ? b_gt : b_gs;

  __shared__ float hcat[2][2 * C];
  __shared__ float gbuf[2][C];
  __shared__ float red[4];
  __shared__ float r26[2][6];

  float agg = 0.f;
#pragma unroll
  for (int j = 0; j < KNN_K; ++j)
    agg += h[(size_t)nbr[b * KNN_K + j] * C + c];
  hcat[half][c] = h[(size_t)b * C + c];
  hcat[half][C + c] = agg * (1.0f / KNN_K);
  __syncthreads();

  float acc = bg[c];
  for (int k = 0; k < 2 * C; ++k) acc += hcat[half][k] * Wg[k * C + c];

  float ss = acc * acc;
#pragma unroll
  for (int off = 32; off; off >>= 1) ss += __shfl_xor(ss, off, 64);
  if (lane == 0) red[wave] = ss;
  __syncthreads();
  const float g = acc / sqrtf(red[half * 2] + red[half * 2 + 1]);
  gbuf[half][c] = g;
  (half ? f_gt_out : f_gs_out)[(size_t)b * C + c] = g;
  __syncthreads();

  if (half == 0) {
    const int id = idx[b];
    const float ml = mem_l[(size_t)id * C + c];
    const float mab = mem_ab[(size_t)id * C + c];
    const float es = f_es[(size_t)b * C + c];
    const float et = f_et[(size_t)b * C + c];
    const float gs = gbuf[0][c];
    const float gt = gbuf[1][c];
    const float sgs = 0.75f * ml + 0.25f * gs;
    const float sgt = 0.75f * mab + 0.25f * gt;

    float v6[6] = {sgs * sgs, sgt * sgt, mab * es, ml * et, sgt * gs, sgs * gt};
#pragma unroll
    for (int q = 0; q < 6; ++q) {
      float v = v6[q];
#pragma unroll
      for (int off = 32; off; off >>= 1) v += __shfl_xor(v, off, 64);
      if (lane == 0) r26[wave][q] = v;
    }
  }
  __syncthreads();
  if (t == 0) {
    const float ss_gs = r26[0][0] + r26[1][0];
    const float ss_gt = r26[0][1] + r26[1][1];
    pos[0 * B + b] = r26[0][2] + r26[1][2];                  // ls_pos
    pos[1 * B + b] = r26[0][3] + r26[1][3];                  // lt_pos
    pos[2 * B + b] = (r26[0][4] + r26[1][4]) / sqrtf(ss_gt); // gs_pos
    pos[3 * B + b] = (r26[0][5] + r26[1][5]) / sqrtf(ss_gs); // gt_pos
  }
}

// ---------------------------------------------------------------------------
// Heavy fused gather kernel over SORTED rows. grid (B, NCHUNK, 2).
// blockIdx.x = b varies fastest -> all resident blocks process the same
// ascending row window of the bank -> L3-localized.
// ---------------------------------------------------------------------------
__global__ __launch_bounds__(256) void neg_partial_kernel(
    const float* __restrict__ mem_l, const float* __restrict__ mem_ab,
    const int* __restrict__ srows, const float* __restrict__ f_es,
    const float* __restrict__ f_et, const float* __restrict__ f_gs,
    const float* __restrict__ f_gt, float* __restrict__ partial) {
  const int b = blockIdx.x;
  const int chunk = blockIdx.y;
  const int bank = blockIdx.z;
  const float* __restrict__ mem = bank ? mem_ab : mem_l;
  const float* __restrict__ f1 = bank ? f_et : f_es;
  const float* __restrict__ f2 = bank ? f_gt : f_gs;
  const int t = threadIdx.x;
  const int wave = t >> 6, lane = t & 63;
  const int grp = t >> 4;   // 0..15
  const int lig = t & 15;   // lane in 16-lane group

  __shared__ int rows[KC];
  __shared__ float rbuf[4][2];

  rows[t] = srows[(size_t)b * KNEG + chunk * KC + t];

  const float4 x1lo = ((const float4*)f1)[b * 32 + lig];
  const float4 x1hi = ((const float4*)f1)[b * 32 + lig + 16];
  const float4 x2lo = ((const float4*)f2)[b * 32 + lig];
  const float4 x2hi = ((const float4*)f2)[b * 32 + lig + 16];
  __syncthreads();

  const float4* pa = (const float4*)(mem + ((size_t)rows[grp * 16 + 0] << 7));
  const float4* pb = (const float4*)(mem + ((size_t)rows[grp * 16 + 1] << 7));
  float4 alo = pa[lig], ahi = pa[lig + 16];
  float4 blo = pb[lig], bhi = pb[lig + 16];

  float s1 = 0.f, s2 = 0.f;
  for (int it = 0; it < 16; it += 2) {
    const float4 calo = alo, cahi = ahi, cblo = blo, cbhi = bhi;
    if (it + 2 < 16) {
      const float4* na = (const float4*)(mem + ((size_t)rows[grp * 16 + it + 2] << 7));
      const float4* nb = (const float4*)(mem + ((size_t)rows[grp * 16 + it + 3] << 7));
      alo = na[lig]; ahi = na[lig + 16];
      blo = nb[lig]; bhi = nb[lig + 16];
    }
    float d1a = dot4(calo, x1lo) + dot4(cahi, x1hi);
    float d2a = dot4(calo, x2lo) + dot4(cahi, x2hi);
    float d1b = dot4(cblo, x1lo) + dot4(cbhi, x1hi);
    float d2b = dot4(cblo, x2lo) + dot4(cbhi, x2hi);
    d1a = sum16(d1a); d2a = sum16(d2a);
    d1b = sum16(d1b); d2b = sum16(d2b);
    s1 += __expf(d1a * TINV) + __expf(d1b * TINV);
    s2 += __expf(d2a * TINV) + __expf(d2b * TINV);
  }
  s1 += __shfl_xor(s1, 32, 64);
  s1 += __shfl_xor(s1, 16, 64);
  s2 += __shfl_xor(s2, 32, 64);
  s2 += __shfl_xor(s2, 16, 64);
  if (lane == 0) { rbuf[wave][0] = s1; rbuf[wave][1] = s2; }
  __syncthreads();
  if (t == 0) {
    const float v1 = rbuf[0][0] + rbuf[1][0] + rbuf[2][0] + rbuf[3][0];
    const float v2 = rbuf[0][1] + rbuf[1][1] + rbuf[2][1] + rbuf[3][1];
    partial[((size_t)bank * B + b) * NCHUNK + chunk] = v1;
    partial[((size_t)(bank + 2) * B + b) * NCHUNK + chunk] = v2;
  }
}

// ---------------------------------------------------------------------------
// Final: loss = sum_l mean_b( log(exp(pos/T) + sum_k exp(neg/T)) - pos/T )
// ---------------------------------------------------------------------------
__global__ __launch_bounds__(256) void loss_kernel(
    const float* __restrict__ partial, const float* __restrict__ pos,
    float* __restrict__ out) {
  const int b = threadIdx.x;
  const int wave = b >> 6, lane = b & 63;
  __shared__ float rb[4];
  float contrib = 0.f;
#pragma unroll
  for (int l = 0; l < 4; ++l) {
    const float p = pos[l * B + b] * TINV;
    float s = expf(p);
    for (int ch = 0; ch < NCHUNK; ++ch)
      s += partial[((size_t)l * B + b) * NCHUNK + ch];
    contrib += logf(s) - p;
  }
#pragma unroll
  for (int off = 32; off; off >>= 1) contrib += __shfl_xor(contrib, off, 64);
  if (lane == 0) rb[wave] = contrib;
  __syncthreads();
  if (b == 0) out[0] = (rb[0] + rb[1] + rb[2] + rb[3]) * (1.0f / B);
}

// ---------------------------------------------------------------------------
extern "C" void kernel_launch(void* const* d_in, const int* in_sizes, int n_in,
                              void* d_out, int out_size, void* d_ws,
                              size_t ws_size, hipStream_t stream) {
  const float* f_s = (const float*)d_in[1];
  const float* l_s = (const float*)d_in[2];
  const float* f_t = (const float*)d_in[3];
  const float* l_t = (const float*)d_in[4];
  const int* idx = (const int*)d_in[5];
  const int* cidx = (const int*)d_in[6];
  const float* W_es = (const float*)d_in[7];
  const float* b_es = (const float*)d_in[8];
  const float* W_et = (const float*)d_in[9];
  const float* b_et = (const float*)d_in[10];
  const float* W_gs = (const float*)d_in[11];
  const float* b_gs = (const float*)d_in[12];
  const float* W_gt = (const float*)d_in[13];
  const float* b_gt = (const float*)d_in[14];
  const float* mem_l = (const float*)d_in[15];
  const float* mem_ab = (const float*)d_in[16];

  char* w = (char*)d_ws;
  float* ws_f_es = (float*)w;    w += B * C * sizeof(float);
  float* ws_f_et = (float*)w;    w += B * C * sizeof(float);
  float* ws_f_gs = (float*)w;    w += B * C * sizeof(float);
  float* ws_f_gt = (float*)w;    w += B * C * sizeof(float);
  float* ws_soft_s = (float*)w;  w += B * NCLS * sizeof(float);
  float* ws_soft_t = (float*)w;  w += B * NCLS * sizeof(float);
  float* ws_wn_s = (float*)w;    w += B * sizeof(float);
  float* ws_wn_t = (float*)w;    w += B * sizeof(float);
  int* ws_nbr_s = (int*)w;       w += B * KNN_K * sizeof(int);
  int* ws_nbr_t = (int*)w;       w += B * KNN_K * sizeof(int);
  float* ws_pos = (float*)w;     w += 4 * B * sizeof(float);
  float* ws_partial = (float*)w; w += 4 * B * NCHUNK * sizeof(float);
  int* ws_sorted = (int*)w;      w += (size_t)B * KNEG * sizeof(int);  // 4 MB

  sort_refs_kernel<<<B, 1024, 0, stream>>>(cidx, ws_sorted);

  embed2_kernel<<<dim3(B / 4, 2), 256, 0, stream>>>(f_s, W_es, b_es, f_t, W_et,
                                                    b_et, ws_f_es, ws_f_et);

  knn_soft_kernel<<<dim3(B, 2), 128, 0, stream>>>(l_s, l_t, ws_soft_s,
                                                  ws_soft_t, ws_wn_s, ws_wn_t);

  knn_topk_kernel<<<dim3(B, 2), 256, 0, stream>>>(ws_soft_s, ws_wn_s, ws_nbr_s,
                                                  ws_soft_t, ws_wn_t, ws_nbr_t);

  gnn_pos_kernel<<<B, 256, 0, stream>>>(ws_f_es, ws_f_et, ws_nbr_s, ws_nbr_t,
                                        W_gs, b_gs, W_gt, b_gt, mem_l, mem_ab,
                                        idx, ws_f_gs, ws_f_gt, ws_pos);

  neg_partial_kernel<<<dim3(B, NCHUNK, 2), 256, 0, stream>>>(
      mem_l, mem_ab, ws_sorted, ws_f_es, ws_f_et, ws_f_gs, ws_f_gt, ws_partial);

  loss_kernel<<<1, 256, 0, stream>>>(ws_partial, ws_pos, (float*)d_out);
}

// Round 6
// 413.253 us; speedup vs baseline: 1.0267x; 1.0267x over previous
//
#include <hip/hip_runtime.h>
#include <math.h>

#define B 256
#define SDIM 1024
#define TDIM 2048
#define C 128
#define NCLS 100
#define KNEG 4096
#define KNN_K 8
#define NCHUNK 16
#define KC (KNEG / NCHUNK)   // 256 rows per block
#define TINV (1.0f / 0.07f)

// ---------------------------------------------------------------------------
// DPP helpers: cross-lane sums on the VALU pipe.
// ---------------------------------------------------------------------------
template <int CTRL>
__device__ __forceinline__ float dpp_add(float v) {
  const int x = __builtin_amdgcn_update_dpp(0, __float_as_int(v), CTRL, 0xF, 0xF, true);
  return v + __int_as_float(x);
}
__device__ __forceinline__ float sum16(float v) {
  v = dpp_add<0xB1>(v);   // quad_perm [1,0,3,2]
  v = dpp_add<0x4E>(v);   // quad_perm [2,3,0,1]
  v = dpp_add<0x141>(v);  // row_half_mirror
  v = dpp_add<0x140>(v);  // row_mirror
  return v;
}
__device__ __forceinline__ float wave_sum64(float v) {
  v = sum16(v);
  v += __shfl_xor(v, 16, 64);
  v += __shfl_xor(v, 32, 64);
  return v;
}
__device__ __forceinline__ float dot4(float4 a, float4 b) {
  return a.x * b.x + a.y * b.y + a.z * b.z + a.w * b.w;
}

// ---------------------------------------------------------------------------
// Per-b deterministic bitonic sort of the 4096 contrast indices by row id.
// Key = (row << 12) | k -> unique keys -> total order -> deterministic.
// ---------------------------------------------------------------------------
__global__ __launch_bounds__(1024) void sort_refs_kernel(
    const int* __restrict__ cidx, int* __restrict__ sorted_rows) {
  __shared__ unsigned key[KNEG];  // 16 KB
  const int b = blockIdx.x;
  const int t = threadIdx.x;

  for (int i = t; i < KNEG; i += 1024)
    key[i] = ((unsigned)cidx[(size_t)b * KNEG + i] << 12) | (unsigned)i;
  __syncthreads();

  for (int k2 = 2; k2 <= KNEG; k2 <<= 1) {
    for (int j = k2 >> 1; j > 0; j >>= 1) {
#pragma unroll
      for (int s = 0; s < KNEG / 1024; ++s) {
        const int i = s * 1024 + t;
        const int ixj = i ^ j;
        if (ixj > i) {
          const bool up = ((i & k2) == 0);
          const unsigned a = key[i], c = key[ixj];
          if ((a > c) == up) { key[i] = c; key[ixj] = a; }
        }
      }
      __syncthreads();
    }
  }
  for (int i = t; i < KNEG; i += 1024)
    sorted_rows[(size_t)b * KNEG + i] = (int)(key[i] >> 12);
}

// ---------------------------------------------------------------------------
// Fused embed, 4 batch rows per block: out[b,:] = l2norm(X[b,:] @ W^T + bias)
// grid (B/4, 2): y=0 -> (f_s,W_es), y=1 -> (f_t,W_et). 256 thr = 4 waves.
// ---------------------------------------------------------------------------
__global__ __launch_bounds__(256) void embed2_kernel(
    const float* __restrict__ Xs, const float* __restrict__ Ws,
    const float* __restrict__ bs, const float* __restrict__ Xt,
    const float* __restrict__ Wt, const float* __restrict__ bt,
    float* __restrict__ out_s, float* __restrict__ out_t) {
  const int which = blockIdx.y;
  const int S = which ? TDIM : SDIM;
  const float* __restrict__ X = which ? Xt : Xs;
  const float* __restrict__ W = which ? Wt : Ws;
  const float* __restrict__ bias = which ? bt : bs;
  float* __restrict__ out = which ? out_t : out_s;

  __shared__ float xrow[4 * TDIM];
  __shared__ float ob[4][C];
  const int b4 = blockIdx.x * 4;
  const int t = threadIdx.x;
  const int wave = t >> 6, lane = t & 63;

  const float4* xg = (const float4*)(X + (size_t)b4 * S);
  for (int i = t; i < S; i += 256) ((float4*)xrow)[i] = xg[i];
  __syncthreads();

  const int nj = S / 256;
  const int sq = S / 4;
  for (int ci = 0; ci < 32; ++ci) {
    const int c = wave * 32 + ci;
    const float4* wrow = (const float4*)(W + (size_t)c * S);
    float a0 = 0.f, a1 = 0.f, a2 = 0.f, a3 = 0.f;
    for (int j = 0; j < nj; ++j) {
      const float4 w4 = wrow[lane + 64 * j];
      a0 += dot4(w4, ((const float4*)xrow)[0 * sq + lane + 64 * j]);
      a1 += dot4(w4, ((const float4*)xrow)[1 * sq + lane + 64 * j]);
      a2 += dot4(w4, ((const float4*)xrow)[2 * sq + lane + 64 * j]);
      a3 += dot4(w4, ((const float4*)xrow)[3 * sq + lane + 64 * j]);
    }
    a0 = wave_sum64(a0); a1 = wave_sum64(a1);
    a2 = wave_sum64(a2); a3 = wave_sum64(a3);
    if (lane == 0) {
      const float bb = bias[c];
      ob[0][c] = a0 + bb; ob[1][c] = a1 + bb;
      ob[2][c] = a2 + bb; ob[3][c] = a3 + bb;
    }
  }
  __syncthreads();

  const float v1 = ob[wave][lane];
  const float v2 = ob[wave][lane + 64];
  const float ss = wave_sum64(v1 * v1 + v2 * v2);
  const float inv = 1.0f / sqrtf(ss);
  out[(size_t)(b4 + wave) * C + lane] = v1 * inv;
  out[(size_t)(b4 + wave) * C + lane + 64] = v2 * inv;
}

// ---------------------------------------------------------------------------
// knn part 1: row softmax of logits [B,NCLS] + L2 norm of softmax row.
// ---------------------------------------------------------------------------
__global__ __launch_bounds__(128) void knn_soft_kernel(
    const float* __restrict__ Ls, const float* __restrict__ Lt,
    float* __restrict__ soft_s, float* __restrict__ soft_t,
    float* __restrict__ wn_s, float* __restrict__ wn_t) {
  const int which = blockIdx.y;
  const float* L = which ? Lt : Ls;
  float* soft = which ? soft_t : soft_s;
  float* wn = which ? wn_t : wn_s;
  const int b = blockIdx.x;
  const int t = threadIdx.x;
  const int wave = t >> 6, lane = t & 63;
  __shared__ float r2[2];

  const float x = (t < NCLS) ? L[b * NCLS + t] : -INFINITY;
  float m = x;
#pragma unroll
  for (int off = 32; off; off >>= 1) m = fmaxf(m, __shfl_xor(m, off, 64));
  if (lane == 0) r2[wave] = m;
  __syncthreads();
  m = fmaxf(r2[0], r2[1]);
  __syncthreads();

  const float e = (t < NCLS) ? expf(x - m) : 0.f;
  float s = e;
#pragma unroll
  for (int off = 32; off; off >>= 1) s += __shfl_xor(s, off, 64);
  if (lane == 0) r2[wave] = s;
  __syncthreads();
  s = r2[0] + r2[1];
  __syncthreads();

  const float p = e / s;
  if (t < NCLS) soft[b * NCLS + t] = p;

  float q = p * p;
#pragma unroll
  for (int off = 32; off; off >>= 1) q += __shfl_xor(q, off, 64);
  if (lane == 0) r2[wave] = q;
  __syncthreads();
  if (t == 0) wn[b] = sqrtf(r2[0] + r2[1]);
}

// ---------------------------------------------------------------------------
// knn part 2: top-8 neighbor set per row. grid (B, 2), 256 threads.
// ---------------------------------------------------------------------------
__global__ __launch_bounds__(256) void knn_topk_kernel(
    const float* __restrict__ soft_s, const float* __restrict__ wn_s,
    int* __restrict__ nbr_s, const float* __restrict__ soft_t,
    const float* __restrict__ wn_t, int* __restrict__ nbr_t) {
  const int which = blockIdx.y;
  const float* __restrict__ soft = which ? soft_t : soft_s;
  const float* __restrict__ wn = which ? wn_t : wn_s;
  int* __restrict__ nbr = which ? nbr_t : nbr_s;

  const int i = blockIdx.x;
  const int j = threadIdx.x;
  __shared__ float si[NCLS];
  __shared__ float vals[B];

  if (j < NCLS) si[j] = soft[i * NCLS + j];
  __syncthreads();

  float dot = 0.f;
  const float4* sj4 = (const float4*)(soft + j * NCLS);
#pragma unroll
  for (int c = 0; c < NCLS / 4; ++c) dot += dot4(((const float4*)si)[c], sj4[c]);
  const float denom = fmaxf(wn[i] * wn[j], 1e-7f);
  vals[j] = (j == i) ? 1.0f : (dot / denom - 1.0f);
  __syncthreads();

  if (j < 64) {
    float v0 = vals[j], v1 = vals[j + 64], v2 = vals[j + 128], v3 = vals[j + 192];
    for (int r = 0; r < KNN_K; ++r) {
      float bv = v0; int bi = j;
      if (v1 > bv) { bv = v1; bi = j + 64; }
      if (v2 > bv) { bv = v2; bi = j + 128; }
      if (v3 > bv) { bv = v3; bi = j + 192; }
#pragma unroll
      for (int off = 1; off < 64; off <<= 1) {
        const float ov = __shfl_xor(bv, off, 64);
        const int oi = __shfl_xor(bi, off, 64);
        if (ov > bv || (ov == bv && oi < bi)) { bv = ov; bi = oi; }
      }
      if (j == 0) nbr[i * KNN_K + r] = bi;
      if (j == (bi & 63)) {
        const int q = bi >> 6;
        if (q == 0) v0 = -INFINITY;
        else if (q == 1) v1 = -INFINITY;
        else if (q == 2) v2 = -INFINITY;
        else v3 = -INFINITY;
      }
    }
  }
}

// ---------------------------------------------------------------------------
// Fused TAGConv(k=1)+l2norm for BOTH branches + all four positive logits.
// ---------------------------------------------------------------------------
__global__ __launch_bounds__(256) void gnn_pos_kernel(
    const float* __restrict__ f_es, const float* __restrict__ f_et,
    const int* __restrict__ nbr_s, const int* __restrict__ nbr_t,
    const float* __restrict__ W_gs, const float* __restrict__ b_gs,
    const float* __restrict__ W_gt, const float* __restrict__ b_gt,
    const float* __restrict__ mem_l, const float* __restrict__ mem_ab,
    const int* __restrict__ idx, float* __restrict__ f_gs_out,
    float* __restrict__ f_gt_out, float* __restrict__ pos) {
  const int b = blockIdx.x;
  const int t = threadIdx.x;
  const int half = t >> 7;
  const int c = t & 127;
  const int wave = t >> 6, lane = t & 63;

  const float* __restrict__ h = half ? f_et : f_es;
  const int* __restrict__ nbr = half ? nbr_t : nbr_s;
  const float* __restrict__ Wg = half ? W_gt : W_gs;
  const float* __restrict__ bg = half ? b_gt : b_gs;

  __shared__ float hcat[2][2 * C];
  __shared__ float gbuf[2][C];
  __shared__ float red[4];
  __shared__ float r26[2][6];

  float agg = 0.f;
#pragma unroll
  for (int j = 0; j < KNN_K; ++j)
    agg += h[(size_t)nbr[b * KNN_K + j] * C + c];
  hcat[half][c] = h[(size_t)b * C + c];
  hcat[half][C + c] = agg * (1.0f / KNN_K);
  __syncthreads();

  float acc = bg[c];
  for (int k = 0; k < 2 * C; ++k) acc += hcat[half][k] * Wg[k * C + c];

  float ss = acc * acc;
#pragma unroll
  for (int off = 32; off; off >>= 1) ss += __shfl_xor(ss, off, 64);
  if (lane == 0) red[wave] = ss;
  __syncthreads();
  const float g = acc / sqrtf(red[half * 2] + red[half * 2 + 1]);
  gbuf[half][c] = g;
  (half ? f_gt_out : f_gs_out)[(size_t)b * C + c] = g;
  __syncthreads();

  if (half == 0) {
    const int id = idx[b];
    const float ml = mem_l[(size_t)id * C + c];
    const float mab = mem_ab[(size_t)id * C + c];
    const float es = f_es[(size_t)b * C + c];
    const float et = f_et[(size_t)b * C + c];
    const float gs = gbuf[0][c];
    const float gt = gbuf[1][c];
    const float sgs = 0.75f * ml + 0.25f * gs;
    const float sgt = 0.75f * mab + 0.25f * gt;

    float v6[6] = {sgs * sgs, sgt * sgt, mab * es, ml * et, sgt * gs, sgs * gt};
#pragma unroll
    for (int q = 0; q < 6; ++q) {
      float v = v6[q];
#pragma unroll
      for (int off = 32; off; off >>= 1) v += __shfl_xor(v, off, 64);
      if (lane == 0) r26[wave][q] = v;
    }
  }
  __syncthreads();
  if (t == 0) {
    const float ss_gs = r26[0][0] + r26[1][0];
    const float ss_gt = r26[0][1] + r26[1][1];
    pos[0 * B + b] = r26[0][2] + r26[1][2];                  // ls_pos
    pos[1 * B + b] = r26[0][3] + r26[1][3];                  // lt_pos
    pos[2 * B + b] = (r26[0][4] + r26[1][4]) / sqrtf(ss_gt); // gs_pos
    pos[3 * B + b] = (r26[0][5] + r26[1][5]) / sqrtf(ss_gs); // gt_pos
  }
}

// ---------------------------------------------------------------------------
// Heavy fused gather kernel over SORTED rows, XCD-affinity scheduling.
// 1-D grid of 8192 blocks. Hardware dispatches linear block id round-robin
// across 8 XCDs (xcd = id % 8, learn_hip m09). We invert that map so each
// (chunk,bank) "window" (256 blocks sharing a ~6.4MB sorted row range) runs
// entirely on ONE XCD: its ~5x cross-b row multiplicity is then served by
// that XCD's 4MB L2 instead of L3/HBM.
//   id = (wq*256 + b)*8 + (window & 7),  window = wq*8 + xcd  (wq = 0..3)
//   window = bank*NCHUNK + chunk
// ---------------------------------------------------------------------------
__global__ __launch_bounds__(256) void neg_partial_kernel(
    const float* __restrict__ mem_l, const float* __restrict__ mem_ab,
    const int* __restrict__ srows, const float* __restrict__ f_es,
    const float* __restrict__ f_et, const float* __restrict__ f_gs,
    const float* __restrict__ f_gt, float* __restrict__ partial) {
  const int id = blockIdx.x;
  const int xcd = id & 7;
  const int q = id >> 3;
  const int b = q & 255;
  const int wq = q >> 8;            // 0..3
  const int window = (wq << 3) | xcd;  // 0..31
  const int chunk = window & (NCHUNK - 1);
  const int bank = window >> 4;

  const float* __restrict__ mem = bank ? mem_ab : mem_l;
  const float* __restrict__ f1 = bank ? f_et : f_es;
  const float* __restrict__ f2 = bank ? f_gt : f_gs;
  const int t = threadIdx.x;
  const int wave = t >> 6, lane = t & 63;
  const int grp = t >> 4;   // 0..15
  const int lig = t & 15;   // lane in 16-lane group

  __shared__ int rows[KC];
  __shared__ float rbuf[4][2];

  rows[t] = srows[(size_t)b * KNEG + chunk * KC + t];

  const float4 x1lo = ((const float4*)f1)[b * 32 + lig];
  const float4 x1hi = ((const float4*)f1)[b * 32 + lig + 16];
  const float4 x2lo = ((const float4*)f2)[b * 32 + lig];
  const float4 x2hi = ((const float4*)f2)[b * 32 + lig + 16];
  __syncthreads();

  const float4* pa = (const float4*)(mem + ((size_t)rows[grp * 16 + 0] << 7));
  const float4* pb = (const float4*)(mem + ((size_t)rows[grp * 16 + 1] << 7));
  float4 alo = pa[lig], ahi = pa[lig + 16];
  float4 blo = pb[lig], bhi = pb[lig + 16];

  float s1 = 0.f, s2 = 0.f;
  for (int it = 0; it < 16; it += 2) {
    const float4 calo = alo, cahi = ahi, cblo = blo, cbhi = bhi;
    if (it + 2 < 16) {
      const float4* na = (const float4*)(mem + ((size_t)rows[grp * 16 + it + 2] << 7));
      const float4* nb = (const float4*)(mem + ((size_t)rows[grp * 16 + it + 3] << 7));
      alo = na[lig]; ahi = na[lig + 16];
      blo = nb[lig]; bhi = nb[lig + 16];
    }
    float d1a = dot4(calo, x1lo) + dot4(cahi, x1hi);
    float d2a = dot4(calo, x2lo) + dot4(cahi, x2hi);
    float d1b = dot4(cblo, x1lo) + dot4(cbhi, x1hi);
    float d2b = dot4(cblo, x2lo) + dot4(cbhi, x2hi);
    d1a = sum16(d1a); d2a = sum16(d2a);
    d1b = sum16(d1b); d2b = sum16(d2b);
    s1 += __expf(d1a * TINV) + __expf(d1b * TINV);
    s2 += __expf(d2a * TINV) + __expf(d2b * TINV);
  }
  s1 += __shfl_xor(s1, 32, 64);
  s1 += __shfl_xor(s1, 16, 64);
  s2 += __shfl_xor(s2, 32, 64);
  s2 += __shfl_xor(s2, 16, 64);
  if (lane == 0) { rbuf[wave][0] = s1; rbuf[wave][1] = s2; }
  __syncthreads();
  if (t == 0) {
    const float v1 = rbuf[0][0] + rbuf[1][0] + rbuf[2][0] + rbuf[3][0];
    const float v2 = rbuf[0][1] + rbuf[1][1] + rbuf[2][1] + rbuf[3][1];
    partial[((size_t)bank * B + b) * NCHUNK + chunk] = v1;
    partial[((size_t)(bank + 2) * B + b) * NCHUNK + chunk] = v2;
  }
}

// ---------------------------------------------------------------------------
// Final: loss = sum_l mean_b( log(exp(pos/T) + sum_k exp(neg/T)) - pos/T )
// ---------------------------------------------------------------------------
__global__ __launch_bounds__(256) void loss_kernel(
    const float* __restrict__ partial, const float* __restrict__ pos,
    float* __restrict__ out) {
  const int b = threadIdx.x;
  const int wave = b >> 6, lane = b & 63;
  __shared__ float rb[4];
  float contrib = 0.f;
#pragma unroll
  for (int l = 0; l < 4; ++l) {
    const float p = pos[l * B + b] * TINV;
    float s = expf(p);
    for (int ch = 0; ch < NCHUNK; ++ch)
      s += partial[((size_t)l * B + b) * NCHUNK + ch];
    contrib += logf(s) - p;
  }
#pragma unroll
  for (int off = 32; off; off >>= 1) contrib += __shfl_xor(contrib, off, 64);
  if (lane == 0) rb[wave] = contrib;
  __syncthreads();
  if (b == 0) out[0] = (rb[0] + rb[1] + rb[2] + rb[3]) * (1.0f / B);
}

// ---------------------------------------------------------------------------
extern "C" void kernel_launch(void* const* d_in, const int* in_sizes, int n_in,
                              void* d_out, int out_size, void* d_ws,
                              size_t ws_size, hipStream_t stream) {
  const float* f_s = (const float*)d_in[1];
  const float* l_s = (const float*)d_in[2];
  const float* f_t = (const float*)d_in[3];
  const float* l_t = (const float*)d_in[4];
  const int* idx = (const int*)d_in[5];
  const int* cidx = (const int*)d_in[6];
  const float* W_es = (const float*)d_in[7];
  const float* b_es = (const float*)d_in[8];
  const float* W_et = (const float*)d_in[9];
  const float* b_et = (const float*)d_in[10];
  const float* W_gs = (const float*)d_in[11];
  const float* b_gs = (const float*)d_in[12];
  const float* W_gt = (const float*)d_in[13];
  const float* b_gt = (const float*)d_in[14];
  const float* mem_l = (const float*)d_in[15];
  const float* mem_ab = (const float*)d_in[16];

  char* w = (char*)d_ws;
  float* ws_f_es = (float*)w;    w += B * C * sizeof(float);
  float* ws_f_et = (float*)w;    w += B * C * sizeof(float);
  float* ws_f_gs = (float*)w;    w += B * C * sizeof(float);
  float* ws_f_gt = (float*)w;    w += B * C * sizeof(float);
  float* ws_soft_s = (float*)w;  w += B * NCLS * sizeof(float);
  float* ws_soft_t = (float*)w;  w += B * NCLS * sizeof(float);
  float* ws_wn_s = (float*)w;    w += B * sizeof(float);
  float* ws_wn_t = (float*)w;    w += B * sizeof(float);
  int* ws_nbr_s = (int*)w;       w += B * KNN_K * sizeof(int);
  int* ws_nbr_t = (int*)w;       w += B * KNN_K * sizeof(int);
  float* ws_pos = (float*)w;     w += 4 * B * sizeof(float);
  float* ws_partial = (float*)w; w += 4 * B * NCHUNK * sizeof(float);
  int* ws_sorted = (int*)w;      w += (size_t)B * KNEG * sizeof(int);  // 4 MB

  sort_refs_kernel<<<B, 1024, 0, stream>>>(cidx, ws_sorted);

  embed2_kernel<<<dim3(B / 4, 2), 256, 0, stream>>>(f_s, W_es, b_es, f_t, W_et,
                                                    b_et, ws_f_es, ws_f_et);

  knn_soft_kernel<<<dim3(B, 2), 128, 0, stream>>>(l_s, l_t, ws_soft_s,
                                                  ws_soft_t, ws_wn_s, ws_wn_t);

  knn_topk_kernel<<<dim3(B, 2), 256, 0, stream>>>(ws_soft_s, ws_wn_s, ws_nbr_s,
                                                  ws_soft_t, ws_wn_t, ws_nbr_t);

  gnn_pos_kernel<<<B, 256, 0, stream>>>(ws_f_es, ws_f_et, ws_nbr_s, ws_nbr_t,
                                        W_gs, b_gs, W_gt, b_gt, mem_l, mem_ab,
                                        idx, ws_f_gs, ws_f_gt, ws_pos);

  neg_partial_kernel<<<B * NCHUNK * 2, 256, 0, stream>>>(
      mem_l, mem_ab, ws_sorted, ws_f_es, ws_f_et, ws_f_gs, ws_f_gt, ws_partial);

  loss_kernel<<<1, 256, 0, stream>>>(ws_partial, ws_pos, (float*)d_out);
}